// Round 5
// baseline (368.306 us; speedup 1.0000x reference)
//
#include <hip/hip_runtime.h>
#include <stdint.h>

typedef __bf16 bf16;
typedef __attribute__((ext_vector_type(4))) float f32x4;
typedef __attribute__((ext_vector_type(8))) __bf16 bf16x8;
typedef __attribute__((ext_vector_type(4))) __bf16 bf16x4;

#define NB 16      // batch
#define CH 512     // channels
#define HWS 1024   // H*W
#define NHEAD 8
#define DH 64
#define O3 1536    // 3*C
#define KLP 64     // XOR-swizzled LDS pitch (bf16): chunk dc stored at dc^(row&7)
#define LDP 72     // padded pitch for Ps
#define CPQ 136    // qkv C-restage pitch (bf16)
#define CPF 132    // proj C-restage pitch (fp32)

// ---------------------------------------------------------------- gn fused (stats + normalize + transpose) and weight cvt
__global__ void gn_fused(const float* __restrict__ x,
                         const float* __restrict__ gamma, const float* __restrict__ beta,
                         const float* __restrict__ wq, const float* __restrict__ wp,
                         bf16* __restrict__ wq_b, bf16* __restrict__ wp_b,
                         bf16* __restrict__ hT) {
    int bx = blockIdx.x;
    int tid = threadIdx.x;
    if (bx >= 512) {                    // ---- weight fp32 -> bf16 tail blocks
        int i = (bx - 512) * 256 + tid;
        if (i < O3*CH) wq_b[i] = (bf16)wq[i];
        else           wp_b[i - O3*CH] = (bf16)wp[i - O3*CH];
        return;
    }
    __shared__ float tile[16*68];
    __shared__ float red[8];
    __shared__ float sm[2];
    int b = bx >> 5, g = bx & 31;
    const float* xg = x + ((size_t)(b * CH + g * 16)) * HWS;   // 16 ch x 1024
    // phase 1: stats
    const float4* p4 = (const float4*)xg;
    float s = 0.f, ss = 0.f;
    for (int i = tid; i < 4096; i += 256) {
        float4 v = p4[i];
        s  += v.x + v.y + v.z + v.w;
        ss += v.x*v.x + v.y*v.y + v.z*v.z + v.w*v.w;
    }
    for (int off = 32; off; off >>= 1) {
        s  += __shfl_xor(s,  off, 64);
        ss += __shfl_xor(ss, off, 64);
    }
    int w = tid >> 6;
    if ((tid & 63) == 0) { red[w*2] = s; red[w*2+1] = ss; }
    __syncthreads();
    if (tid == 0) {
        float S  = red[0] + red[2] + red[4] + red[6];
        float SS = red[1] + red[3] + red[5] + red[7];
        float mean = S * (1.f/16384.f);
        float var  = SS * (1.f/16384.f) - mean*mean;
        sm[0] = mean;
        sm[1] = rsqrtf(var + 1e-5f);
    }
    __syncthreads();
    float mean = sm[0], rstd = sm[1];
    // phase 2: normalize + transpose 16x64 tiles (reads hit L2)
    int cl = tid >> 4, nl4 = (tid & 15) * 4;     // load role
    float sc = rstd * gamma[g*16 + cl];
    float sh = beta[g*16 + cl] - mean * sc;
    int nw = tid >> 2, c4 = tid & 3;             // store role
    for (int nt = 0; nt < 16; ++nt) {
        int n0 = nt * 64;
        float4 v = *(const float4*)(xg + (size_t)cl * HWS + n0 + nl4);
        float4 t;
        t.x = v.x*sc + sh; t.y = v.y*sc + sh; t.z = v.z*sc + sh; t.w = v.w*sc + sh;
        *(float4*)&tile[cl*68 + nl4] = t;
        __syncthreads();
        bf16x4 o;
        #pragma unroll
        for (int j = 0; j < 4; ++j) o[j] = (bf16)tile[(c4*4 + j)*68 + nw];
        *(bf16x4*)(hT + ((size_t)(b * HWS + n0 + nw)) * CH + g*16 + c4*4) = o;
        __syncthreads();
    }
}

// ---------------------------------------------------------------- qkv GEMM + fused V-transpose
// D[o][bn] = sum_c Wq[o][c]*hT[bn][c].  Q/K -> qkv[bn][o] via LDS restage; V -> vT direct.
__global__ __launch_bounds__(256, 3)
void qkv_gemm(const bf16* __restrict__ W, const bf16* __restrict__ hT,
              const float* __restrict__ bias, bf16* __restrict__ qkv,
              bf16* __restrict__ vT) {
    __shared__ __align__(16) bf16 SMEM[128*CPQ];   // 34816B; staging uses first 32KB
    bf16* As = SMEM;                 // W tile [128 o][64k], XOR-swizzled
    bf16* Bs = SMEM + 128*KLP;       // hT tile [128 bn][64k]
    int bx = blockIdx.x;                 // 12 * 128 = 1536
    int po = bx >> 7, qo = bx & 127;     // qo low bits -> XCD locality on hT
    int obase = po*128, bnbase = qo*128;
    int tid = threadIdx.x;
    int lane = tid & 63, w = tid >> 6;
    int quad = lane >> 4, l15 = lane & 15;
    int wm = w >> 1, wn = w & 1;
    int x7 = l15 & 7;

    uint4 pa[4], pb[4];
    #pragma unroll
    for (int r = 0; r < 4; ++r) {
        int c = r*256 + tid, row = c >> 3, dc = c & 7;
        pa[r] = *(const uint4*)(W  + ((size_t)(obase + row)) * 512 + dc*8);
        pb[r] = *(const uint4*)(hT + ((size_t)(bnbase + row)) * 512 + dc*8);
    }

    f32x4 acc[4][4] = {};
    for (int k0 = 0; k0 < 512; k0 += 64) {
        #pragma unroll
        for (int r = 0; r < 4; ++r) {
            int c = r*256 + tid, row = c >> 3, dc = c & 7;
            int pc = row*KLP + ((dc ^ (row & 7)) * 8);
            *(uint4*)(&As[pc]) = pa[r];
            *(uint4*)(&Bs[pc]) = pb[r];
        }
        __syncthreads();
        if (k0 < 448) {
            #pragma unroll
            for (int r = 0; r < 4; ++r) {
                int c = r*256 + tid, row = c >> 3, dc = c & 7;
                pa[r] = *(const uint4*)(W  + ((size_t)(obase + row)) * 512 + k0 + 64 + dc*8);
                pb[r] = *(const uint4*)(hT + ((size_t)(bnbase + row)) * 512 + k0 + 64 + dc*8);
            }
        }
        #pragma unroll
        for (int ks = 0; ks < 2; ++ks) {
            int ch = (ks*4 + quad) ^ x7;
            bf16x8 af[4], bfv[4];
            #pragma unroll
            for (int mt = 0; mt < 4; ++mt)
                af[mt] = *(const bf16x8*)(&As[(wm*64 + mt*16 + l15)*KLP + ch*8]);
            #pragma unroll
            for (int nt = 0; nt < 4; ++nt)
                bfv[nt] = *(const bf16x8*)(&Bs[(wn*64 + nt*16 + l15)*KLP + ch*8]);
            #pragma unroll
            for (int mt = 0; mt < 4; ++mt)
                #pragma unroll
                for (int nt = 0; nt < 4; ++nt)
                    acc[mt][nt] = __builtin_amdgcn_mfma_f32_16x16x32_bf16(af[mt], bfv[nt], acc[mt][nt], 0, 0, 0);
        }
        __syncthreads();
    }

    // ---- epilogue: bias, V-direct stores, C restage for Q/K
    bf16* Cs = SMEM;                 // [128 bn][CPQ]
    int b = bnbase >> 10;
    int nbase = bnbase & 1023;
    #pragma unroll
    for (int mt = 0; mt < 4; ++mt) {
        int o0 = obase + wm*64 + mt*16 + quad*4;
        float4 bb = *(const float4*)(bias + o0);
        int c192 = o0 % 192;
        bool isV = (c192 >= 128);
        int h = o0 / 192;
        int d0 = c192 - 128;
        #pragma unroll
        for (int nt = 0; nt < 4; ++nt) {
            int bn_l = wn*64 + nt*16 + l15;
            bf16x4 v;
            v[0] = (bf16)(acc[mt][nt][0] + bb.x);
            v[1] = (bf16)(acc[mt][nt][1] + bb.y);
            v[2] = (bf16)(acc[mt][nt][2] + bb.z);
            v[3] = (bf16)(acc[mt][nt][3] + bb.w);
            *(bf16x4*)(&Cs[bn_l*CPQ + (o0 - obase)]) = v;
            if (isV) {
                int key = nbase + bn_l;
                size_t vb_ = ((size_t)((b*8 + h)*64 + d0)) * HWS + key;
                vT[vb_]          = v[0];
                vT[vb_ + HWS]    = v[1];
                vT[vb_ + 2*HWS]  = v[2];
                vT[vb_ + 3*HWS]  = v[3];
            }
        }
    }
    __syncthreads();
    #pragma unroll
    for (int p = 0; p < 8; ++p) {
        int bn_l = p*16 + (tid >> 4);
        int o8 = (tid & 15) * 8;
        if ((obase + o8) % 192 < 128) {
            uint4 v = *(const uint4*)(&Cs[bn_l*CPQ + o8]);
            *(uint4*)(qkv + ((size_t)(bnbase + bn_l)) * O3 + obase + o8) = v;
        }
    }
}

// ---------------------------------------------------------------- flash attention (v4)
// Double-buffered K/V (XOR swizzle), ONE barrier per kt; 3 blocks/CU.
__global__ __launch_bounds__(256, 3)
void flash_attn(const bf16* __restrict__ qkv, const bf16* __restrict__ vT,
                bf16* __restrict__ A2) {
    __shared__ __align__(16) bf16 Kd[2][64*KLP];
    __shared__ __align__(16) bf16 Vd[2][64*KLP];
    __shared__ __align__(16) bf16 Ps[4][32*LDP];
    int bx = blockIdx.x;                 // 1024: g = bx&127 (XCD locality), qt = bx>>7
    int g = bx & 127, qt = bx >> 7;
    int b = g >> 3, h = g & 7;
    int tid = threadIdx.x, lane = tid & 63, w = tid >> 6;
    int quad = lane >> 4, l15 = lane & 15;
    int x7 = l15 & 7;
    const float kLog2 = 0.04419417382415922f * 1.44269504088896341f; // 512^-0.5 * log2(e)

    bf16x8 aq[2][2];
    #pragma unroll
    for (int mt = 0; mt < 2; ++mt) {
        int qrow = qt*128 + w*32 + mt*16 + l15;
        const bf16* qb = qkv + ((size_t)(b * HWS + qrow)) * O3 + h*192;
        aq[mt][0] = *(const bf16x8*)(qb + quad*8);
        aq[mt][1] = *(const bf16x8*)(qb + 32 + quad*8);
    }

    f32x4 acc[2][4] = {};
    float L[2] = {0.f, 0.f};

    int r0 = tid >> 3, dc = tid & 7, d0 = dc * 8;
    int r1 = r0 + 32;                      // r1&7 == r0&7
    int sOff0 = r0*KLP + ((dc ^ (r0 & 7)) * 8);
    int sOff1 = r1*KLP + ((dc ^ (r0 & 7)) * 8);
    const bf16* kp0 = qkv + ((size_t)(b * HWS + r0)) * O3 + h*192 + 64 + d0;
    const bf16* kp1 = qkv + ((size_t)(b * HWS + r1)) * O3 + h*192 + 64 + d0;
    const bf16* vp0 = vT + ((size_t)(g * DH + r0)) * HWS + d0;
    const bf16* vp1 = vT + ((size_t)(g * DH + r1)) * HWS + d0;

    uint4 ka = *(const uint4*)(kp0);
    uint4 kb = *(const uint4*)(kp1);
    uint4 va = *(const uint4*)(vp0);
    uint4 vb = *(const uint4*)(vp1);

    for (int kt = 0; kt < 16; ++kt) {
        bf16* Kb = &Kd[kt & 1][0];
        bf16* Vb = &Vd[kt & 1][0];
        *(uint4*)(Kb + sOff0) = ka;
        *(uint4*)(Kb + sOff1) = kb;
        *(uint4*)(Vb + sOff0) = va;
        *(uint4*)(Vb + sOff1) = vb;
        __syncthreads();
        if (kt < 15) {
            size_t ko = (size_t)(kt+1) * 64 * O3;
            size_t vo = (size_t)(kt+1) * 64;
            ka = *(const uint4*)(kp0 + ko);
            kb = *(const uint4*)(kp1 + ko);
            va = *(const uint4*)(vp0 + vo);
            vb = *(const uint4*)(vp1 + vo);
        }

        // S^T = K x Q^T: lane holds q=l15, keys nt*16+quad*4+r; exp inline
        #pragma unroll
        for (int nt = 0; nt < 4; ++nt) {
            int ro = (nt*16 + l15)*KLP;
            bf16x8 ak0 = *(const bf16x8*)(&Kb[ro + ((quad ^ x7)*8)]);
            bf16x8 ak1 = *(const bf16x8*)(&Kb[ro + (((4 + quad) ^ x7)*8)]);
            #pragma unroll
            for (int mt = 0; mt < 2; ++mt) {
                f32x4 z = {};
                z = __builtin_amdgcn_mfma_f32_16x16x32_bf16(ak0, aq[mt][0], z, 0, 0, 0);
                z = __builtin_amdgcn_mfma_f32_16x16x32_bf16(ak1, aq[mt][1], z, 0, 0, 0);
                bf16x4 p;
                #pragma unroll
                for (int r = 0; r < 4; ++r) {
                    float e = exp2f(z[r] * kLog2);
                    L[mt] += e;
                    p[r] = (bf16)e;
                }
                *(bf16x4*)(&Ps[w][(mt*16 + l15)*LDP + nt*16 + quad*4]) = p;
            }
        }
        // PV: A=P (wave-private), B=V^T
        bf16x8 ap[2][2];
        #pragma unroll
        for (int mt = 0; mt < 2; ++mt) {
            ap[mt][0] = *(const bf16x8*)(&Ps[w][(mt*16 + l15)*LDP + quad*8]);
            ap[mt][1] = *(const bf16x8*)(&Ps[w][(mt*16 + l15)*LDP + 32 + quad*8]);
        }
        #pragma unroll
        for (int dt = 0; dt < 4; ++dt) {
            int ro = (dt*16 + l15)*KLP;
            bf16x8 bv0 = *(const bf16x8*)(&Vb[ro + ((quad ^ x7)*8)]);
            bf16x8 bv1 = *(const bf16x8*)(&Vb[ro + (((4 + quad) ^ x7)*8)]);
            #pragma unroll
            for (int mt = 0; mt < 2; ++mt) {
                acc[mt][dt] = __builtin_amdgcn_mfma_f32_16x16x32_bf16(ap[mt][0], bv0, acc[mt][dt], 0, 0, 0);
                acc[mt][dt] = __builtin_amdgcn_mfma_f32_16x16x32_bf16(ap[mt][1], bv1, acc[mt][dt], 0, 0, 0);
            }
        }
    }

    float Linv[2][4];
    #pragma unroll
    for (int mt = 0; mt < 2; ++mt) {
        float Lf = L[mt];
        Lf += __shfl_xor(Lf, 16, 64);
        Lf += __shfl_xor(Lf, 32, 64);
        #pragma unroll
        for (int r = 0; r < 4; ++r)
            Linv[mt][r] = 1.f / __shfl(Lf, quad*4 + r, 64);
    }

    __syncthreads();
    #pragma unroll
    for (int mt = 0; mt < 2; ++mt)
        #pragma unroll
        for (int dt = 0; dt < 4; ++dt)
            #pragma unroll
            for (int r = 0; r < 4; ++r)
                Ps[w][(mt*16 + quad*4 + r)*LDP + dt*16 + l15] = (bf16)(acc[mt][dt][r] * Linv[mt][r]);

    int bp = g & 15;          // output batch (reference's head-major quirk)
    int hp = g >> 4;          // output head slot
    #pragma unroll
    for (int cc = 0; cc < 4; ++cc) {
        int c = cc*64 + lane;
        int row = c >> 3, dcc = c & 7;
        uint4 v = *(const uint4*)(&Ps[w][row*LDP + dcc*8]);
        size_t idx = ((size_t)(bp * HWS + qt*128 + w*32 + row)) * CH + hp*64 + dcc*8;
        *(uint4*)(A2 + idx) = v;
    }
}

// ---------------------------------------------------------------- proj GEMM + bias + residual
__global__ __launch_bounds__(256, 3)
void proj_gemm(const bf16* __restrict__ A2, const bf16* __restrict__ Wp,
               const float* __restrict__ bias, const float* __restrict__ x,
               float* __restrict__ out) {
    __shared__ __align__(16) bf16 SMEM[16896];     // 33792B: staging 32KB | Cf 33792B
    bf16* As = SMEM;                 // A2 tile [128 bn][64k], XOR-swizzled
    bf16* Bs = SMEM + 128*KLP;       // Wp tile [128 o][64k]
    int bx = blockIdx.x;                 // 512
    int po = bx >> 7, qo = bx & 127;
    int obase = po*128, bnbase = qo*128;
    int tid = threadIdx.x;
    int lane = tid & 63, w = tid >> 6;
    int quad = lane >> 4, l15 = lane & 15;
    int wm = w >> 1, wn = w & 1;
    int x7 = l15 & 7;

    uint4 pa[4], pb[4];
    #pragma unroll
    for (int r = 0; r < 4; ++r) {
        int c = r*256 + tid, row = c >> 3, dc = c & 7;
        pa[r] = *(const uint4*)(A2 + ((size_t)(bnbase + row)) * 512 + dc*8);
        pb[r] = *(const uint4*)(Wp + ((size_t)(obase + row)) * 512 + dc*8);
    }

    f32x4 acc[4][4] = {};
    for (int k0 = 0; k0 < 512; k0 += 64) {
        #pragma unroll
        for (int r = 0; r < 4; ++r) {
            int c = r*256 + tid, row = c >> 3, dc = c & 7;
            int pc = row*KLP + ((dc ^ (row & 7)) * 8);
            *(uint4*)(&As[pc]) = pa[r];
            *(uint4*)(&Bs[pc]) = pb[r];
        }
        __syncthreads();
        if (k0 < 448) {
            #pragma unroll
            for (int r = 0; r < 4; ++r) {
                int c = r*256 + tid, row = c >> 3, dc = c & 7;
                pa[r] = *(const uint4*)(A2 + ((size_t)(bnbase + row)) * 512 + k0 + 64 + dc*8);
                pb[r] = *(const uint4*)(Wp + ((size_t)(obase + row)) * 512 + k0 + 64 + dc*8);
            }
        }
        #pragma unroll
        for (int ks = 0; ks < 2; ++ks) {
            int ch = (ks*4 + quad) ^ x7;
            bf16x8 af[4], bfv[4];
            #pragma unroll
            for (int mt = 0; mt < 4; ++mt)
                af[mt] = *(const bf16x8*)(&As[(wm*64 + mt*16 + l15)*KLP + ch*8]);
            #pragma unroll
            for (int nt = 0; nt < 4; ++nt)
                bfv[nt] = *(const bf16x8*)(&Bs[(wn*64 + nt*16 + l15)*KLP + ch*8]);
            #pragma unroll
            for (int mt = 0; mt < 4; ++mt)
                #pragma unroll
                for (int nt = 0; nt < 4; ++nt)
                    acc[mt][nt] = __builtin_amdgcn_mfma_f32_16x16x32_bf16(af[mt], bfv[nt], acc[mt][nt], 0, 0, 0);
        }
        __syncthreads();
    }

    // epilogue: acc[mt][nt][r]: bn = bnbase + wm*64 + mt*16 + quad*4 + r, o = obase + wn*64 + nt*16 + l15
    float* Cf = (float*)SMEM;        // [64 bn][CPF] fp32 per half-pass
    int bb = bnbase >> 10;
    int nbase = bnbase & 1023;
    #pragma unroll
    for (int hh = 0; hh < 2; ++hh) {
        if (wm == hh) {
            #pragma unroll
            for (int mt = 0; mt < 4; ++mt)
                #pragma unroll
                for (int nt = 0; nt < 4; ++nt)
                    #pragma unroll
                    for (int r = 0; r < 4; ++r)
                        Cf[(mt*16 + quad*4 + r)*CPF + wn*64 + nt*16 + l15] = acc[mt][nt][r];
        }
        __syncthreads();
        #pragma unroll
        for (int p = 0; p < 4; ++p) {
            int ol = p*32 + (tid >> 3);
            int nl0 = (tid & 7) * 8;
            int o = obase + ol;
            float bv = bias[o];
            #pragma unroll
            for (int jj = 0; jj < 2; ++jj) {
                int nl = nl0 + jj*4;
                size_t idx = ((size_t)(bb * CH + o)) * HWS + nbase + hh*64 + nl;
                float4 xr = *(const float4*)(x + idx);
                float4 res;
                res.x = Cf[(nl+0)*CPF + ol] + bv + xr.x;
                res.y = Cf[(nl+1)*CPF + ol] + bv + xr.y;
                res.z = Cf[(nl+2)*CPF + ol] + bv + xr.z;
                res.w = Cf[(nl+3)*CPF + ol] + bv + xr.w;
                *(float4*)(out + idx) = res;
            }
        }
        __syncthreads();
    }
}

// ---------------------------------------------------------------- launch
extern "C" void kernel_launch(void* const* d_in, const int* in_sizes, int n_in,
                              void* d_out, int out_size, void* d_ws, size_t ws_size,
                              hipStream_t stream) {
    const float* x      = (const float*)d_in[0];
    const float* gamma  = (const float*)d_in[1];
    const float* beta   = (const float*)d_in[2];
    const float* w_qkv  = (const float*)d_in[3];
    const float* b_qkv  = (const float*)d_in[4];
    const float* w_proj = (const float*)d_in[5];
    const float* b_proj = (const float*)d_in[6];
    float* out = (float*)d_out;

    char* ws = (char*)d_ws;
    bf16*  wq_b  = (bf16*)(ws + 4096);                     // 1.5 MB
    bf16*  wp_b  = (bf16*)(ws + 1576960);                  // 0.5 MB
    bf16*  hT    = (bf16*)(ws + 2101248);                  // 16 MB (aliased by A2 later)
    bf16*  qkv   = (bf16*)(ws + 18878464);                 // 48 MB (V slots unused)
    bf16*  vT    = (bf16*)(ws + 69210112);                 // 16 MB
    bf16*  A2    = hT;                                     // reuse: hT dead after qkv_gemm

    gn_fused  <<<4608, 256, 0, stream>>>(x, gamma, beta, w_qkv, w_proj, wq_b, wp_b, hT);
    qkv_gemm  <<<1536, 256, 0, stream>>>(wq_b, hT, b_qkv, qkv, vT);
    flash_attn<<<1024, 256, 0, stream>>>(qkv, vT, A2);
    proj_gemm <<<512,  256, 0, stream>>>(A2, wp_b, b_proj, x, out);
}

// Round 6
// 220.786 us; speedup vs baseline: 1.6682x; 1.6682x over previous
//
#include <hip/hip_runtime.h>
#include <stdint.h>

typedef __bf16 bf16;
typedef __attribute__((ext_vector_type(4))) float f32x4;
typedef __attribute__((ext_vector_type(8))) __bf16 bf16x8;
typedef __attribute__((ext_vector_type(4))) __bf16 bf16x4;

#define NB 16      // batch
#define CH 512     // channels
#define HWS 1024   // H*W
#define NHEAD 8
#define DH 64
#define O3 1536    // 3*C
#define KLP 64     // XOR-swizzled LDS pitch (bf16): chunk dc stored at dc^(row&7)
#define LDP 72     // padded LDS pitch
#define CPQ 136    // qkv C-restage pitch (bf16)
#define CPF 132    // proj C-restage pitch (fp32)

// ---------------------------------------------------------------- prep: gn stats + weight cvt (round-4)
__global__ void prep(const float* __restrict__ x, float* __restrict__ stats,
                     const float* __restrict__ wq, const float* __restrict__ wp,
                     bf16* __restrict__ wq_b, bf16* __restrict__ wp_b) {
    int bx = blockIdx.x;
    if (bx < 512) {                 // groupnorm stats: b*32+g
        int b = bx >> 5, g = bx & 31;
        const float4* p = (const float4*)(x + ((size_t)(b * CH + g * 16)) * HWS);
        float s = 0.f, ss = 0.f;
        for (int i = threadIdx.x; i < 4096; i += 256) {
            float4 v = p[i];
            s  += v.x + v.y + v.z + v.w;
            ss += v.x*v.x + v.y*v.y + v.z*v.z + v.w*v.w;
        }
        for (int off = 32; off; off >>= 1) {
            s  += __shfl_xor(s,  off, 64);
            ss += __shfl_xor(ss, off, 64);
        }
        __shared__ float red[8];
        int w = threadIdx.x >> 6;
        if ((threadIdx.x & 63) == 0) { red[w*2] = s; red[w*2+1] = ss; }
        __syncthreads();
        if (threadIdx.x == 0) {
            float S  = red[0] + red[2] + red[4] + red[6];
            float SS = red[1] + red[3] + red[5] + red[7];
            float mean = S * (1.f/16384.f);
            float var  = SS * (1.f/16384.f) - mean*mean;
            stats[bx*2]   = mean;
            stats[bx*2+1] = rsqrtf(var + 1e-5f);
        }
    } else {                        // weight fp32 -> bf16
        int i = (bx - 512) * 256 + threadIdx.x;
        if (i < O3*CH) wq_b[i] = (bf16)wq[i];
        else           wp_b[i - O3*CH] = (bf16)wp[i - O3*CH];
    }
}

// ---------------------------------------------------------------- normalize + transpose -> hT (16384,512) bf16 (round-4)
__global__ void gn_apply_t(const float* __restrict__ x, const float* __restrict__ stats,
                           const float* __restrict__ gamma, const float* __restrict__ beta,
                           bf16* __restrict__ hT) {
    __shared__ float tile[32][33];
    int bx = blockIdx.x;            // 16 * 16 * 32 = 8192 blocks
    int b = bx >> 9;
    int rem = bx & 511;
    int ct = rem >> 5, nt = rem & 31;
    int tx = threadIdx.x & 31, ty = threadIdx.x >> 5;   // ty 0..7
    #pragma unroll
    for (int r = 0; r < 4; ++r) {
        int c = ct*32 + ty + r*8;
        int n = nt*32 + tx;
        float v = x[((size_t)(b * CH + c)) * HWS + n];
        int g = c >> 4;
        float mean = stats[(b*32+g)*2], rstd = stats[(b*32+g)*2+1];
        tile[ty + r*8][tx] = (v - mean) * rstd * gamma[c] + beta[c];
    }
    __syncthreads();
    #pragma unroll
    for (int r = 0; r < 4; ++r) {
        int n = nt*32 + ty + r*8;
        int c = ct*32 + tx;
        hT[((size_t)(b * HWS + n)) * CH + c] = (bf16)tile[tx][ty + r*8];
    }
}

// ---------------------------------------------------------------- qkv GEMM + fused V-transpose (round-4 exact)
__global__ __launch_bounds__(256, 3)
void qkv_gemm(const bf16* __restrict__ W, const bf16* __restrict__ hT,
              const float* __restrict__ bias, bf16* __restrict__ qkv,
              bf16* __restrict__ vT) {
    __shared__ __align__(16) bf16 SMEM[2*128*LDP];
    bf16* As = SMEM;                 // W tile, rows = o
    bf16* Bs = SMEM + 128*LDP;       // hT tile, rows = bn
    int bx = blockIdx.x;                 // 12 * 128 = 1536 blocks
    int po = bx >> 7, qo = bx & 127;     // qo in low bits -> XCD locality on hT
    int obase = po*128, bnbase = qo*128;
    int tid = threadIdx.x;
    int lane = tid & 63, w = tid >> 6;
    int quad = lane >> 4, l15 = lane & 15;
    int wm = w >> 1, wn = w & 1;

    f32x4 acc[4][4] = {};
    for (int k0 = 0; k0 < 512; k0 += 64) {
        #pragma unroll
        for (int r = 0; r < 4; ++r) {
            int c = r*256 + tid;
            int row = c >> 3, dc = c & 7;
            uint4 va = *(const uint4*)(W  + ((size_t)(obase + row)) * 512 + k0 + dc*8);
            *(uint4*)(&As[row*LDP + dc*8]) = va;
            uint4 vb = *(const uint4*)(hT + ((size_t)(bnbase + row)) * 512 + k0 + dc*8);
            *(uint4*)(&Bs[row*LDP + dc*8]) = vb;
        }
        __syncthreads();
        #pragma unroll
        for (int ks = 0; ks < 2; ++ks) {
            bf16x8 af[4], bfv[4];
            #pragma unroll
            for (int mt = 0; mt < 4; ++mt)
                af[mt] = *(const bf16x8*)(&As[(wm*64 + mt*16 + l15)*LDP + ks*32 + quad*8]);
            #pragma unroll
            for (int nt = 0; nt < 4; ++nt)
                bfv[nt] = *(const bf16x8*)(&Bs[(wn*64 + nt*16 + l15)*LDP + ks*32 + quad*8]);
            #pragma unroll
            for (int mt = 0; mt < 4; ++mt)
                #pragma unroll
                for (int nt = 0; nt < 4; ++nt)
                    acc[mt][nt] = __builtin_amdgcn_mfma_f32_16x16x32_bf16(af[mt], bfv[nt], acc[mt][nt], 0, 0, 0);
        }
        __syncthreads();
    }

    // ---- epilogue: bias, V-direct stores, C restage for Q/K
    bf16* Cs = SMEM;                 // [128 bn][CPQ]
    int b = bnbase >> 10;
    int nbase = bnbase & 1023;
    #pragma unroll
    for (int mt = 0; mt < 4; ++mt) {
        int o0 = obase + wm*64 + mt*16 + quad*4;
        float4 bb = *(const float4*)(bias + o0);
        int c192 = o0 % 192;
        bool isV = (c192 >= 128);
        int h = o0 / 192;
        int d0 = c192 - 128;
        #pragma unroll
        for (int nt = 0; nt < 4; ++nt) {
            int bn_l = wn*64 + nt*16 + l15;
            bf16x4 v;
            v[0] = (bf16)(acc[mt][nt][0] + bb.x);
            v[1] = (bf16)(acc[mt][nt][1] + bb.y);
            v[2] = (bf16)(acc[mt][nt][2] + bb.z);
            v[3] = (bf16)(acc[mt][nt][3] + bb.w);
            *(bf16x4*)(&Cs[bn_l*CPQ + (o0 - obase)]) = v;
            if (isV) {
                int key = nbase + bn_l;
                size_t vb_ = ((size_t)((b*8 + h)*64 + d0)) * HWS + key;
                vT[vb_]          = v[0];
                vT[vb_ + HWS]    = v[1];
                vT[vb_ + 2*HWS]  = v[2];
                vT[vb_ + 3*HWS]  = v[3];
            }
        }
    }
    __syncthreads();
    #pragma unroll
    for (int p = 0; p < 8; ++p) {
        int bn_l = p*16 + (tid >> 4);
        int o8 = (tid & 15) * 8;
        if ((obase + o8) % 192 < 128) {
            uint4 v = *(const uint4*)(&Cs[bn_l*CPQ + o8]);
            *(uint4*)(qkv + ((size_t)(bnbase + bn_l)) * O3 + obase + o8) = v;
        }
    }
}

// ---------------------------------------------------------------- flash attention (v4, kept from round 5)
// Double-buffered K/V (XOR swizzle), ONE barrier per kt; 3 blocks/CU.
__global__ __launch_bounds__(256, 3)
void flash_attn(const bf16* __restrict__ qkv, const bf16* __restrict__ vT,
                bf16* __restrict__ A2) {
    __shared__ __align__(16) bf16 Kd[2][64*KLP];
    __shared__ __align__(16) bf16 Vd[2][64*KLP];
    __shared__ __align__(16) bf16 Ps[4][32*LDP];
    int bx = blockIdx.x;                 // 1024: g = bx&127 (XCD locality), qt = bx>>7
    int g = bx & 127, qt = bx >> 7;
    int b = g >> 3, h = g & 7;
    int tid = threadIdx.x, lane = tid & 63, w = tid >> 6;
    int quad = lane >> 4, l15 = lane & 15;
    int x7 = l15 & 7;
    const float kLog2 = 0.04419417382415922f * 1.44269504088896341f; // 512^-0.5 * log2(e)

    bf16x8 aq[2][2];
    #pragma unroll
    for (int mt = 0; mt < 2; ++mt) {
        int qrow = qt*128 + w*32 + mt*16 + l15;
        const bf16* qb = qkv + ((size_t)(b * HWS + qrow)) * O3 + h*192;
        aq[mt][0] = *(const bf16x8*)(qb + quad*8);
        aq[mt][1] = *(const bf16x8*)(qb + 32 + quad*8);
    }

    f32x4 acc[2][4] = {};
    float L[2] = {0.f, 0.f};

    int r0 = tid >> 3, dc = tid & 7, d0 = dc * 8;
    int r1 = r0 + 32;                      // r1&7 == r0&7
    int sOff0 = r0*KLP + ((dc ^ (r0 & 7)) * 8);
    int sOff1 = r1*KLP + ((dc ^ (r0 & 7)) * 8);
    const bf16* kp0 = qkv + ((size_t)(b * HWS + r0)) * O3 + h*192 + 64 + d0;
    const bf16* kp1 = qkv + ((size_t)(b * HWS + r1)) * O3 + h*192 + 64 + d0;
    const bf16* vp0 = vT + ((size_t)(g * DH + r0)) * HWS + d0;
    const bf16* vp1 = vT + ((size_t)(g * DH + r1)) * HWS + d0;

    uint4 ka = *(const uint4*)(kp0);
    uint4 kb = *(const uint4*)(kp1);
    uint4 va = *(const uint4*)(vp0);
    uint4 vb = *(const uint4*)(vp1);

    for (int kt = 0; kt < 16; ++kt) {
        bf16* Kb = &Kd[kt & 1][0];
        bf16* Vb = &Vd[kt & 1][0];
        *(uint4*)(Kb + sOff0) = ka;
        *(uint4*)(Kb + sOff1) = kb;
        *(uint4*)(Vb + sOff0) = va;
        *(uint4*)(Vb + sOff1) = vb;
        __syncthreads();
        if (kt < 15) {
            size_t ko = (size_t)(kt+1) * 64 * O3;
            size_t vo = (size_t)(kt+1) * 64;
            ka = *(const uint4*)(kp0 + ko);
            kb = *(const uint4*)(kp1 + ko);
            va = *(const uint4*)(vp0 + vo);
            vb = *(const uint4*)(vp1 + vo);
        }

        // S^T = K x Q^T: lane holds q=l15, keys nt*16+quad*4+r; exp inline
        #pragma unroll
        for (int nt = 0; nt < 4; ++nt) {
            int ro = (nt*16 + l15)*KLP;
            bf16x8 ak0 = *(const bf16x8*)(&Kb[ro + ((quad ^ x7)*8)]);
            bf16x8 ak1 = *(const bf16x8*)(&Kb[ro + (((4 + quad) ^ x7)*8)]);
            #pragma unroll
            for (int mt = 0; mt < 2; ++mt) {
                f32x4 z = {};
                z = __builtin_amdgcn_mfma_f32_16x16x32_bf16(ak0, aq[mt][0], z, 0, 0, 0);
                z = __builtin_amdgcn_mfma_f32_16x16x32_bf16(ak1, aq[mt][1], z, 0, 0, 0);
                bf16x4 p;
                #pragma unroll
                for (int r = 0; r < 4; ++r) {
                    float e = exp2f(z[r] * kLog2);
                    L[mt] += e;
                    p[r] = (bf16)e;
                }
                *(bf16x4*)(&Ps[w][(mt*16 + l15)*LDP + nt*16 + quad*4]) = p;
            }
        }
        // PV: A=P (wave-private), B=V^T
        bf16x8 ap[2][2];
        #pragma unroll
        for (int mt = 0; mt < 2; ++mt) {
            ap[mt][0] = *(const bf16x8*)(&Ps[w][(mt*16 + l15)*LDP + quad*8]);
            ap[mt][1] = *(const bf16x8*)(&Ps[w][(mt*16 + l15)*LDP + 32 + quad*8]);
        }
        #pragma unroll
        for (int dt = 0; dt < 4; ++dt) {
            int ro = (dt*16 + l15)*KLP;
            bf16x8 bv0 = *(const bf16x8*)(&Vb[ro + ((quad ^ x7)*8)]);
            bf16x8 bv1 = *(const bf16x8*)(&Vb[ro + (((4 + quad) ^ x7)*8)]);
            #pragma unroll
            for (int mt = 0; mt < 2; ++mt) {
                acc[mt][dt] = __builtin_amdgcn_mfma_f32_16x16x32_bf16(ap[mt][0], bv0, acc[mt][dt], 0, 0, 0);
                acc[mt][dt] = __builtin_amdgcn_mfma_f32_16x16x32_bf16(ap[mt][1], bv1, acc[mt][dt], 0, 0, 0);
            }
        }
    }

    float Linv[2][4];
    #pragma unroll
    for (int mt = 0; mt < 2; ++mt) {
        float Lf = L[mt];
        Lf += __shfl_xor(Lf, 16, 64);
        Lf += __shfl_xor(Lf, 32, 64);
        #pragma unroll
        for (int r = 0; r < 4; ++r)
            Linv[mt][r] = 1.f / __shfl(Lf, quad*4 + r, 64);
    }

    __syncthreads();
    #pragma unroll
    for (int mt = 0; mt < 2; ++mt)
        #pragma unroll
        for (int dt = 0; dt < 4; ++dt)
            #pragma unroll
            for (int r = 0; r < 4; ++r)
                Ps[w][(mt*16 + quad*4 + r)*LDP + dt*16 + l15] = (bf16)(acc[mt][dt][r] * Linv[mt][r]);

    int bp = g & 15;          // output batch (reference's head-major quirk)
    int hp = g >> 4;          // output head slot
    #pragma unroll
    for (int cc = 0; cc < 4; ++cc) {
        int c = cc*64 + lane;
        int row = c >> 3, dcc = c & 7;
        uint4 v = *(const uint4*)(&Ps[w][row*LDP + dcc*8]);
        size_t idx = ((size_t)(bp * HWS + qt*128 + w*32 + row)) * CH + hp*64 + dcc*8;
        *(uint4*)(A2 + idx) = v;
    }
}

// ---------------------------------------------------------------- proj GEMM + bias + residual (round-4 exact)
__global__ __launch_bounds__(256, 3)
void proj_gemm(const bf16* __restrict__ A2, const bf16* __restrict__ Wp,
               const float* __restrict__ bias, const float* __restrict__ x,
               float* __restrict__ out) {
    __shared__ __align__(16) bf16 SMEM[2*128*LDP];
    bf16* As = SMEM;                 // A2 tile, rows = bn
    bf16* Bs = SMEM + 128*LDP;       // Wp tile, rows = o
    int bx = blockIdx.x;                 // 512: po = o-tile, qo = bn-tile
    int po = bx >> 7, qo = bx & 127;
    int obase = po*128, bnbase = qo*128;
    int tid = threadIdx.x;
    int lane = tid & 63, w = tid >> 6;
    int quad = lane >> 4, l15 = lane & 15;
    int wm = w >> 1, wn = w & 1;

    f32x4 acc[4][4] = {};
    for (int k0 = 0; k0 < 512; k0 += 64) {
        #pragma unroll
        for (int r = 0; r < 4; ++r) {
            int c = r*256 + tid;
            int row = c >> 3, dc = c & 7;
            uint4 va = *(const uint4*)(A2 + ((size_t)(bnbase + row)) * 512 + k0 + dc*8);
            *(uint4*)(&As[row*LDP + dc*8]) = va;
            uint4 vb = *(const uint4*)(Wp + ((size_t)(obase + row)) * 512 + k0 + dc*8);
            *(uint4*)(&Bs[row*LDP + dc*8]) = vb;
        }
        __syncthreads();
        #pragma unroll
        for (int ks = 0; ks < 2; ++ks) {
            bf16x8 af[4], bfv[4];
            #pragma unroll
            for (int mt = 0; mt < 4; ++mt)
                af[mt] = *(const bf16x8*)(&As[(wm*64 + mt*16 + l15)*LDP + ks*32 + quad*8]);
            #pragma unroll
            for (int nt = 0; nt < 4; ++nt)
                bfv[nt] = *(const bf16x8*)(&Bs[(wn*64 + nt*16 + l15)*LDP + ks*32 + quad*8]);
            #pragma unroll
            for (int mt = 0; mt < 4; ++mt)
                #pragma unroll
                for (int nt = 0; nt < 4; ++nt)
                    acc[mt][nt] = __builtin_amdgcn_mfma_f32_16x16x32_bf16(af[mt], bfv[nt], acc[mt][nt], 0, 0, 0);
        }
        __syncthreads();
    }

    // epilogue: acc[mt][nt][r]: bn = bnbase + wm*64 + mt*16 + quad*4 + r, o = obase + wn*64 + nt*16 + l15
    float* Cf = (float*)SMEM;        // [64 bn][CPF] fp32 per half-pass
    int bb = bnbase >> 10;
    int nbase = bnbase & 1023;
    #pragma unroll
    for (int hh = 0; hh < 2; ++hh) {
        if (wm == hh) {
            #pragma unroll
            for (int mt = 0; mt < 4; ++mt)
                #pragma unroll
                for (int nt = 0; nt < 4; ++nt)
                    #pragma unroll
                    for (int r = 0; r < 4; ++r)
                        Cf[(mt*16 + quad*4 + r)*CPF + wn*64 + nt*16 + l15] = acc[mt][nt][r];
        }
        __syncthreads();
        #pragma unroll
        for (int p = 0; p < 4; ++p) {
            int ol = p*32 + (tid >> 3);
            int nl0 = (tid & 7) * 8;
            int o = obase + ol;
            float bv = bias[o];
            #pragma unroll
            for (int jj = 0; jj < 2; ++jj) {
                int nl = nl0 + jj*4;
                size_t idx = ((size_t)(bb * CH + o)) * HWS + nbase + hh*64 + nl;
                float4 xr = *(const float4*)(x + idx);
                float4 res;
                res.x = Cf[(nl+0)*CPF + ol] + bv + xr.x;
                res.y = Cf[(nl+1)*CPF + ol] + bv + xr.y;
                res.z = Cf[(nl+2)*CPF + ol] + bv + xr.z;
                res.w = Cf[(nl+3)*CPF + ol] + bv + xr.w;
                *(float4*)(out + idx) = res;
            }
        }
        __syncthreads();
    }
}

// ---------------------------------------------------------------- launch
extern "C" void kernel_launch(void* const* d_in, const int* in_sizes, int n_in,
                              void* d_out, int out_size, void* d_ws, size_t ws_size,
                              hipStream_t stream) {
    const float* x      = (const float*)d_in[0];
    const float* gamma  = (const float*)d_in[1];
    const float* beta   = (const float*)d_in[2];
    const float* w_qkv  = (const float*)d_in[3];
    const float* b_qkv  = (const float*)d_in[4];
    const float* w_proj = (const float*)d_in[5];
    const float* b_proj = (const float*)d_in[6];
    float* out = (float*)d_out;

    char* ws = (char*)d_ws;
    float* stats = (float*)(ws + 0);                       //   4 KB
    bf16*  wq_b  = (bf16*)(ws + 4096);                     // 1.5 MB
    bf16*  wp_b  = (bf16*)(ws + 1576960);                  // 0.5 MB
    bf16*  hT    = (bf16*)(ws + 2101248);                  // 16 MB (aliased by A2 later)
    bf16*  qkv   = (bf16*)(ws + 18878464);                 // 48 MB (V slots unused)
    bf16*  vT    = (bf16*)(ws + 69210112);                 // 16 MB
    bf16*  A2    = hT;                                     // reuse: hT dead after qkv_gemm

    prep       <<<4608, 256, 0, stream>>>(x, stats, w_qkv, w_proj, wq_b, wp_b);
    gn_apply_t <<<8192, 256, 0, stream>>>(x, stats, gamma, beta, hT);
    qkv_gemm   <<<1536, 256, 0, stream>>>(wq_b, hT, b_qkv, qkv, vT);
    flash_attn <<<1024, 256, 0, stream>>>(qkv, vT, A2);
    proj_gemm  <<<512,  256, 0, stream>>>(A2, wp_b, b_proj, x, out);
}